// Round 1
// 302.142 us; speedup vs baseline: 1.0630x; 1.0630x over previous
//
#include <hip/hip_runtime.h>
#include <hip/hip_bf16.h>
#include <cstdint>
#include <cstddef>

#define B_ 16
#define TX_ 256
#define TY_ 2048
#define C_ 80
#define H_ 256
#define NEG_ -1e9f
#define NEG_I (int)0xCE6E6B28   // bit pattern of -1e9f

// one backtrace step at column-in-chunk jb from row ii, using window pair W
// (rows 8p..8p+7) with fallback Wl (rows 8p-8..8p-1).
// Bit layout (carry-push in fwd): bit(row r, col jb) at 4*(7-jb) + r within
// each 32-bit word; high word of the u64 holds rows 8p+4..8p+7.
#define BT_STEP(JB)                                                           \
    {                                                                         \
        unsigned bit = ((unsigned)(W >> (((ii & 4) << 3)                      \
                                         | ((7 - (JB)) << 2)                  \
                                         | (ii & 3))) & 1u)                   \
                     & (unsigned)(ii > 0);                                    \
        ii -= (int)bit;                                                       \
        W = (bit && ((ii & 7) == 7)) ? Wl : W;                                \
    }

// ---------------------------------------------------------------------------
// Kernel 1: logp[b,x,t] = -0.5*( S1 - 2*S2 + T3[x] )/C - 0.5*mean_c(ls[x])
// Register tile: 16 x * 4 t per thread. Also emits transposed logp_t [B,Ty,Tx]
// (into the attn slot of d_out) so MAS reads DP columns coalesced.
// ---------------------------------------------------------------------------
__global__ __launch_bounds__(256) void logp_kernel(
    const float* __restrict__ mu, const float* __restrict__ ls,
    const float* __restrict__ y, float* __restrict__ logp_out,
    float* __restrict__ logp_t)
{
    __shared__ float2 coef[16 * 80];
    __shared__ float  aux[16 * 80];
    __shared__ float  Kx[16];
    __shared__ float  yt[16 * 1028];

    const int tid = threadIdx.x;
    const int t0 = blockIdx.x * 1024;
    const int x0 = blockIdx.y * 16;
    const int b  = blockIdx.z;

    for (int i = tid; i < 16 * 80; i += 256) {
        int c = i >> 4, x = i & 15;
        float m = mu[(size_t)(b * C_ + c) * TX_ + x0 + x];
        float l = ls[(size_t)(b * C_ + c) * TX_ + x0 + x];
        float w = __expf(-2.f * l);
        coef[x * 80 + c] = make_float2(w, -2.f * m * w);
        aux[x * 80 + c]  = fmaf(m * m, w, l);
    }
    __syncthreads();
    if (tid < 16) {
        float s = 0.f;
        for (int c = 0; c < C_; ++c) s += aux[tid * 80 + c];
        Kx[tid] = -0.5f * s / (float)C_;
    }

    float acc[16][4];
#pragma unroll
    for (int x = 0; x < 16; ++x)
#pragma unroll
        for (int r = 0; r < 4; ++r) acc[x][r] = 0.f;

    const float4* y4 = (const float4*)y;
    for (int c0 = 0; c0 < C_; c0 += 16) {
        __syncthreads();
        for (int it = 0; it < 16; ++it) {
            int f = tid + it * 256;
            int t = f >> 2, k = f & 3;
            float4 v = y4[(size_t)(b * TY_ + t0 + t) * 20 + (c0 >> 2) + k];
            yt[(4 * k + 0) * 1028 + t] = v.x;
            yt[(4 * k + 1) * 1028 + t] = v.y;
            yt[(4 * k + 2) * 1028 + t] = v.z;
            yt[(4 * k + 3) * 1028 + t] = v.w;
        }
        __syncthreads();
        for (int cl = 0; cl < 16; ++cl) {
            const float4 yv = *reinterpret_cast<const float4*>(&yt[cl * 1028 + 4 * tid]);
            float4 y2 = make_float4(yv.x * yv.x, yv.y * yv.y, yv.z * yv.z, yv.w * yv.w);
#pragma unroll
            for (int x = 0; x < 16; ++x) {
                float2 f2 = coef[x * 80 + c0 + cl];
                acc[x][0] = fmaf(y2.x, f2.x, fmaf(yv.x, f2.y, acc[x][0]));
                acc[x][1] = fmaf(y2.y, f2.x, fmaf(yv.y, f2.y, acc[x][1]));
                acc[x][2] = fmaf(y2.z, f2.x, fmaf(yv.z, f2.y, acc[x][2]));
                acc[x][3] = fmaf(y2.w, f2.x, fmaf(yv.w, f2.y, acc[x][3]));
            }
        }
    }

#pragma unroll
    for (int x = 0; x < 16; ++x) {
        float kx = Kx[x];
#pragma unroll
        for (int r = 0; r < 4; ++r) acc[x][r] = fmaf(acc[x][r], -0.5f / (float)C_, kx);
        float4 out = make_float4(acc[x][0], acc[x][1], acc[x][2], acc[x][3]);
        *reinterpret_cast<float4*>(
            &logp_out[(size_t)(b * TX_ + x0 + x) * TY_ + t0 + 4 * tid]) = out;
    }
#pragma unroll
    for (int r = 0; r < 4; ++r) {
#pragma unroll
        for (int q = 0; q < 4; ++q) {
            float4 out = make_float4(acc[4 * q + 0][r], acc[4 * q + 1][r],
                                     acc[4 * q + 2][r], acc[4 * q + 3][r]);
            *reinterpret_cast<float4*>(
                &logp_t[(size_t)(b * TY_ + t0 + 4 * tid + r) * TX_ + x0 + 4 * q]) = out;
        }
    }
}

// ---------------------------------------------------------------------------
// Kernel 2a: MAS forward. Single wave per batch, NO LDS, NO barriers.
// Direct global->VGPR column loads, 32-deep software pipeline (counted vmcnt).
// Diag bits packed MSB-first via v_cmp + v_addc carry-push (2 instr/bit).
// ---------------------------------------------------------------------------
#define PD_ 32   // pipeline depth (columns in flight)

#define DP_STEP(CVAL, KC)                                                     \
    {                                                                         \
        int shi = __builtin_amdgcn_update_dpp(                                \
            NEG_I, __float_as_int(v3), 0x138 /*wave_shr1*/, 0xF, 0xF, false); \
        float sh0 = __int_as_float(shi);                                      \
        asm("v_cmp_gt_f32 vcc, %5, %6\n\t"                                    \
            "v_addc_co_u32 %0, vcc, %1, %1, vcc\n\t"                          \
            "v_cmp_gt_f32 vcc, %4, %5\n\t"                                    \
            "v_addc_co_u32 %0, vcc, %0, %0, vcc\n\t"                          \
            "v_cmp_gt_f32 vcc, %3, %4\n\t"                                    \
            "v_addc_co_u32 %0, vcc, %0, %0, vcc\n\t"                          \
            "v_cmp_gt_f32 vcc, %2, %3\n\t"                                    \
            "v_addc_co_u32 %0, vcc, %0, %0, vcc\n\t"                          \
            : "=&v"(accb)                                                     \
            : "v"(accb), "v"(sh0), "v"(v0), "v"(v1), "v"(v2), "v"(v3)         \
            : "vcc");                                                         \
        float m0 = fmaxf(v0, sh0);                                            \
        float m1 = fmaxf(v1, v0);                                             \
        float m2 = fmaxf(v2, v1);                                             \
        float m3 = fmaxf(v3, v2);                                             \
        v0 = m0 + (CVAL).x; v1 = m1 + (CVAL).y;                               \
        v2 = m2 + (CVAL).z; v3 = m3 + (CVAL).w;                               \
        if (((KC) & 7) == 7) {                                                \
            diag[((KC) >> 3) * 64 + lane] = accb;                             \
            accb = 0u;                                                        \
        }                                                                     \
    }

__global__ __launch_bounds__(64, 1) void mas_fwd_kernel(
    const float* __restrict__ logp_t, unsigned int* __restrict__ diag_g)
{
    const int lane = threadIdx.x;
    const int b = blockIdx.x;

    const float* colp = logp_t + (size_t)b * TY_ * TX_ + lane * 4;
    unsigned int* diag = diag_g + (size_t)b * (TY_ / 8) * 64;  // [chunk8][word]

    float v0 = (lane == 0) ? 0.f : NEG_, v1 = NEG_, v2 = NEG_, v3 = NEG_;
    unsigned int accb = 0;

    float4 pre[PD_];
#pragma unroll
    for (int j = 0; j < PD_; ++j)
        pre[j] = *reinterpret_cast<const float4*>(colp + (size_t)j * 256);

    // main loop: process pre[j] (col k0+j), refill with col k0+PD_+j
    for (int k0 = 0; k0 < TY_ - PD_; k0 += PD_) {
        const float* nxt = colp + (size_t)(k0 + PD_) * 256;
#pragma unroll
        for (int j = 0; j < PD_; ++j) {
            float4 c = pre[j];
            pre[j] = *reinterpret_cast<const float4*>(nxt + (size_t)j * 256);
            DP_STEP(c, k0 + j)
        }
    }
    // epilogue: last PD_ columns, no refill
    {
        const int k0 = TY_ - PD_;
#pragma unroll
        for (int j = 0; j < PD_; ++j) {
            float4 c = pre[j];
            DP_STEP(c, k0 + j)
        }
    }
}

// ---------------------------------------------------------------------------
// Kernel 2b: exit-table build. E_c[i] = row after walking chunk c (8 cols)
// entered at row i. grid (16 chunk-groups, 16 b) x 256 thr -> 256 blocks,
// 16 entries/thread, fully parallel across the whole GPU.
// ---------------------------------------------------------------------------
__global__ __launch_bounds__(256) void mas_tab_kernel(
    const unsigned int* __restrict__ diag_g, unsigned char* __restrict__ E_g)
{
    const int t  = threadIdx.x;        // entry row
    const int cg = blockIdx.x;         // chunk group of 16
    const int b  = blockIdx.y;
    const unsigned int* dg = diag_g + (size_t)b * (TY_ / 8) * 64;
    unsigned char* Eb = E_g + (size_t)b * (TY_ / 8) * 256;
    const int p = t >> 3;

    for (int k = 0; k < 16; ++k) {
        const int c = cg * 16 + k;
        unsigned long long W  = *(const unsigned long long*)&dg[c * 64 + 2 * p];
        unsigned long long Wl = p > 0
            ? *(const unsigned long long*)&dg[c * 64 + 2 * (p - 1)] : 0ULL;
        int ii = t;
#pragma unroll
        for (int jb = 7; jb >= 0; --jb) BT_STEP(jb)
        Eb[c * 256 + t] = (unsigned char)ii;
    }
}

// ---------------------------------------------------------------------------
// Kernel 2c: MAS backtrace via exit tables. Serial part is now only the
// 255-step chunk-entry chain (dependent LDS byte reads); emission of all
// 8-column chunks runs in parallel (1 thread/chunk). dr via LDS histogram.
// ---------------------------------------------------------------------------
__global__ __launch_bounds__(256) void mas_bt_kernel(
    const unsigned int* __restrict__ diag_g, const unsigned char* __restrict__ E_g,
    const int* __restrict__ xlen, const int* __restrict__ ylen,
    float* __restrict__ dr_out, int* __restrict__ idx_out)
{
    __shared__ unsigned char E[256 * 256];      // 64 KiB
    __shared__ unsigned char entry_s[256];
    __shared__ int rows_l[TY_];                 // 8 KiB
    __shared__ int cnt_l[TX_];                  // 1 KiB
    const int tid = threadIdx.x;
    const int b = blockIdx.x;
    const int x_len = xlen[b];
    const int y_len = ylen[b];

    cnt_l[tid] = 0;

    // copy E tables global->LDS, coalesced uint4
    const uint4* srcE = (const uint4*)(E_g + (size_t)b * (TY_ / 8) * 256);
    uint4* dstE = (uint4*)E;
#pragma unroll
    for (int it = 0; it < 16; ++it)
        dstE[tid + it * 256] = srcE[tid + it * 256];
    __syncthreads();

    const unsigned int* dg = diag_g + (size_t)b * (TY_ / 8) * 64;
    int* ib = idx_out + (size_t)b * TY_;
    const int jc = (y_len - 1) >> 3;

    if (tid == 0) {
        // partial top chunk (columns y_len-1 .. 8*jc), serial <=8 steps
        int ii = x_len - 1;
        int p = ii >> 3;
        unsigned long long W  = *(const unsigned long long*)&dg[jc * 64 + 2 * p];
        unsigned long long Wl = p > 0
            ? *(const unsigned long long*)&dg[jc * 64 + 2 * (p - 1)] : 0ULL;
        for (int jb = (y_len - 1) & 7; jb >= 0; --jb) {
            int j = 8 * jc + jb;
            ib[j] = ii; rows_l[j] = ii;
            BT_STEP(jb)
        }
        // entry chain over full chunks: 255 dependent LDS byte reads
        int cur = ii;
        for (int c = jc - 1; c >= 0; --c) {
            entry_s[c] = (unsigned char)cur;
            cur = E[c * 256 + cur];
        }
    }
    __syncthreads();

    // parallel emission: one thread per full chunk
    if (tid < jc) {
        const int c = tid;
        int ii = entry_s[c];
        int p = ii >> 3;
        unsigned long long W  = *(const unsigned long long*)&dg[c * 64 + 2 * p];
        unsigned long long Wl = p > 0
            ? *(const unsigned long long*)&dg[c * 64 + 2 * (p - 1)] : 0ULL;
        int r[8];
#pragma unroll
        for (int jb = 7; jb >= 0; --jb) {
            r[jb] = ii;
            BT_STEP(jb)
        }
        *reinterpret_cast<int4*>(&ib[8 * c])     = make_int4(r[0], r[1], r[2], r[3]);
        *reinterpret_cast<int4*>(&ib[8 * c + 4]) = make_int4(r[4], r[5], r[6], r[7]);
        *reinterpret_cast<int4*>(&rows_l[8 * c])     = make_int4(r[0], r[1], r[2], r[3]);
        *reinterpret_cast<int4*>(&rows_l[8 * c + 4]) = make_int4(r[4], r[5], r[6], r[7]);
    }
    __syncthreads();

    // dr[i] = #{ j < y_len : row(j) == i }
    for (int t = tid; t < TY_; t += 256)
        if (t < y_len) atomicAdd(&cnt_l[rows_l[t]], 1);
    __syncthreads();
    dr_out[(size_t)b * TX_ + tid] = (float)cnt_l[tid];
}

// ---------------------------------------------------------------------------
// Kernel 3: emit attn (one-hot path) and o_en_ex (gather of en rows).
// ---------------------------------------------------------------------------
__global__ __launch_bounds__(256) void emit_kernel(
    const float* __restrict__ en, const int* __restrict__ ylen,
    const int* __restrict__ idx_in, float* __restrict__ o_en,
    float* __restrict__ attn)
{
    const int tid = threadIdx.x;
    const int b = blockIdx.x;
    const int r = blockIdx.y;
    const int y_len = ylen[b];
    const int* ib = idx_in + (size_t)b * TY_;

    if (r < 256) {
        const int x = r;
        float* out = attn + ((size_t)b * TX_ + x) * TY_;
        for (int t = tid; t < TY_; t += 256) {
            int ii = ib[t];
            out[t] = (t < y_len && ii == x) ? 1.f : 0.f;
        }
    } else {
        const int h = r - 256;
        __shared__ float enr[256];
        enr[tid] = en[((size_t)b * H_ + h) * TX_ + tid];
        __syncthreads();
        float* out = o_en + ((size_t)b * H_ + h) * TY_;
        for (int t = tid; t < TY_; t += 256) {
            int ii = ib[t];
            bool a = (t < y_len);
            int is = a ? ii : 0;
            out[t] = a ? enr[is] : 0.f;
        }
    }
}

// ---------------------------------------------------------------------------
extern "C" void kernel_launch(void* const* d_in, const int* in_sizes, int n_in,
                              void* d_out, int out_size, void* d_ws, size_t ws_size,
                              hipStream_t stream)
{
    const float* en = (const float*)d_in[0];
    const float* mu = (const float*)d_in[1];
    const float* ls = (const float*)d_in[2];
    const float* y  = (const float*)d_in[3];
    const int* xl   = (const int*)d_in[4];
    const int* yl   = (const int*)d_in[5];

    float* o_en = (float*)d_out;                       // [16,256,2048]
    float* attn = o_en + (size_t)B_ * TX_ * TY_;       // [16,256,2048]
    float* dr   = attn + (size_t)B_ * TX_ * TY_;       // [16,256]
    float* logp = dr + (size_t)B_ * TX_;               // [16,256,2048]

    float* logp_t = attn;                              // scratch in attn slot
    // diag scratch in the o_en slot (1 MB; emit overwrites later)
    unsigned int* diag_g = (unsigned int*)o_en;
    // exit tables E in the logp_t region (dead after mas_fwd; 1 MB)
    unsigned char* E_g = (unsigned char*)logp_t;
    int* idxArr = (int*)d_ws;                          // [16,2048]

    dim3 g1(2, 16, 16);
    logp_kernel<<<g1, 256, 0, stream>>>(mu, ls, y, logp, logp_t);

    mas_fwd_kernel<<<dim3(16), dim3(64), 0, stream>>>(logp_t, diag_g);
    mas_tab_kernel<<<dim3(16, 16), dim3(256), 0, stream>>>(diag_g, E_g);
    mas_bt_kernel<<<dim3(16), dim3(256), 0, stream>>>(diag_g, E_g, xl, yl, dr, idxArr);

    dim3 g3(16, 512);
    emit_kernel<<<g3, 256, 0, stream>>>(en, yl, idxArr, o_en, attn);
}